// Round 5
// baseline (1023.818 us; speedup 1.0000x reference)
//
#include <hip/hip_runtime.h>

typedef __attribute__((ext_vector_type(4))) float f32x4;
typedef _Float16 f16;
typedef __attribute__((ext_vector_type(2))) _Float16 f16x2;
typedef __attribute__((ext_vector_type(8))) _Float16 f16x8;

#define T_LEN 2048
#define B_SZ 256
#define FEATN 128
#define H 50
#define H3 150
#define XW_STRIDE 160

__device__ __forceinline__ float rcpf(float x) { return __builtin_amdgcn_rcpf(x); }

__device__ __forceinline__ float dot2f(f16x2 a, f16x2 b, float c) {
#if __has_builtin(__builtin_amdgcn_fdot2)
  return __builtin_amdgcn_fdot2(a, b, c, false);
#else
  return fmaf((float)a[1], (float)b[1], fmaf((float)a[0], (float)b[0], c));
#endif
}

// ---------------- Phase 1: xw[m][k] = x[m][:] @ W[:][k]  (f16 out, no bias) ----
__global__ __launch_bounds__(256) void xw_gemm(const float* __restrict__ x,
                                               const float* __restrict__ W,
                                               f16* __restrict__ xw) {
  __shared__ f16 Wt[160 * 136];  // [n][k], row stride 136 halves
  const int tid = threadIdx.x;
  for (int idx = tid; idx < FEATN * H3; idx += 256) {
    int f = idx / H3;
    int n = idx - f * H3;
    Wt[n * 136 + f] = (f16)W[idx];
  }
  for (int idx = tid; idx < 10 * FEATN; idx += 256) {  // zero-pad n = 150..159
    int n = H3 + (idx >> 7);
    int f = idx & 127;
    Wt[n * 136 + f] = (f16)0.f;
  }
  __syncthreads();

  const int wid = tid >> 6;
  const int lane = tid & 63;
  const int l15 = lane & 15;
  const int g = lane >> 4;
  const long row0 = (long)blockIdx.x * 128 + wid * 32;

  f16x8 a[2][4];
#pragma unroll
  for (int sub = 0; sub < 2; ++sub) {
    const float* xp = x + (row0 + sub * 16 + l15) * FEATN + g * 8;
#pragma unroll
    for (int kk = 0; kk < 4; ++kk) {
      f32x4 p0 = *(const f32x4*)(xp + kk * 32);
      f32x4 p1 = *(const f32x4*)(xp + kk * 32 + 4);
      f16x8 v;
      v[0] = (f16)p0[0]; v[1] = (f16)p0[1]; v[2] = (f16)p0[2]; v[3] = (f16)p0[3];
      v[4] = (f16)p1[0]; v[5] = (f16)p1[1]; v[6] = (f16)p1[2]; v[7] = (f16)p1[3];
      a[sub][kk] = v;
    }
  }

  for (int nt = 0; nt < 10; ++nt) {
    const f16* bp = &Wt[(nt * 16 + l15) * 136 + g * 8];
    f16x8 bf0 = *(const f16x8*)(bp);
    f16x8 bf1 = *(const f16x8*)(bp + 32);
    f16x8 bf2 = *(const f16x8*)(bp + 64);
    f16x8 bf3 = *(const f16x8*)(bp + 96);
    f32x4 acc0 = {0.f, 0.f, 0.f, 0.f};
    f32x4 acc1 = {0.f, 0.f, 0.f, 0.f};
    acc0 = __builtin_amdgcn_mfma_f32_16x16x32_f16(a[0][0], bf0, acc0, 0, 0, 0);
    acc0 = __builtin_amdgcn_mfma_f32_16x16x32_f16(a[0][1], bf1, acc0, 0, 0, 0);
    acc0 = __builtin_amdgcn_mfma_f32_16x16x32_f16(a[0][2], bf2, acc0, 0, 0, 0);
    acc0 = __builtin_amdgcn_mfma_f32_16x16x32_f16(a[0][3], bf3, acc0, 0, 0, 0);
    acc1 = __builtin_amdgcn_mfma_f32_16x16x32_f16(a[1][0], bf0, acc1, 0, 0, 0);
    acc1 = __builtin_amdgcn_mfma_f32_16x16x32_f16(a[1][1], bf1, acc1, 0, 0, 0);
    acc1 = __builtin_amdgcn_mfma_f32_16x16x32_f16(a[1][2], bf2, acc1, 0, 0, 0);
    acc1 = __builtin_amdgcn_mfma_f32_16x16x32_f16(a[1][3], bf3, acc1, 0, 0, 0);
    int col = nt * 16 + l15;
    if (col < H3) {
#pragma unroll
      for (int r = 0; r < 4; ++r) {
        long rowA = row0 + g * 4 + r;
        xw[rowA * XW_STRIDE + col] = (f16)acc0[r];
        xw[(rowA + 16) * XW_STRIDE + col] = (f16)acc1[r];
      }
    }
  }
}

// ---------------- Phase 2: one wave64 per row; register h, bpermute bcast ----
// Lane l<50 owns h[l]. Per step: DPP quad_perm fetches h[l^1], cvt_pkrtz packs
// the pair (canonical at even lanes), 25 ds_bpermute with constant lane index
// broadcast pair p from lane 2p to all lanes (no LDS store->load round trip).
// 6 split dot2 accumulator chains consume pairs as they return.
__global__ __launch_bounds__(64, 1) void gru_head64(const f16* __restrict__ xw,
                                                    const float* __restrict__ U,
                                                    const float* __restrict__ bias,
                                                    const float* __restrict__ W2,
                                                    const float* __restrict__ b2,
                                                    float* __restrict__ out) {
  __shared__ float fin[52];
  __shared__ float red[8];
  const int l = threadIdx.x;
  const int b = blockIdx.x;
  const int lc = l < H ? l : H - 1;
  const bool act = l < H;
  const long base = (long)b * T_LEN * XW_STRIDE;

  // U columns (z,r,h) for this lane, packed as f16 pairs over j: 75 VGPRs.
  f16x2 uz2[25], ur2[25], uh2[25];
#pragma unroll
  for (int c = 0; c < 25; ++c) {
    uz2[c][0] = (f16)U[(2 * c) * H3 + lc];
    uz2[c][1] = (f16)U[(2 * c + 1) * H3 + lc];
    ur2[c][0] = (f16)U[(2 * c) * H3 + H + lc];
    ur2[c][1] = (f16)U[(2 * c + 1) * H3 + H + lc];
    uh2[c][0] = (f16)U[(2 * c) * H3 + 2 * H + lc];
    uh2[c][1] = (f16)U[(2 * c + 1) * H3 + 2 * H + lc];
  }
  const float bz = bias[lc] + bias[H3 + lc];
  const float br = bias[H + lc] + bias[H3 + H + lc];
  const float b0h = bias[2 * H + lc];
  const float b1h = bias[H3 + 2 * H + lc];

  float hreg = 0.f;

  // prefetch ring, depth 8 (branch-free wrapped addresses)
  f16 pz[8], pr[8], ph[8];
#pragma unroll
  for (int p = 0; p < 8; ++p) {
    long o = base + (long)p * XW_STRIDE;
    pz[p] = xw[o + lc];
    pr[p] = xw[o + H + lc];
    ph[p] = xw[o + 2 * H + lc];
  }

  for (int t0 = 0; t0 < T_LEN; t0 += 8) {
#define STEP(P)                                                               \
    {                                                                         \
      int own = __builtin_bit_cast(int, hreg);                                \
      int par = __builtin_amdgcn_update_dpp(0, own, 0xB1, 0xF, 0xF, true);    \
      int pki = __builtin_bit_cast(                                           \
          int,                                                                \
          __builtin_amdgcn_cvt_pkrtz(hreg, __builtin_bit_cast(float, par))); \
      float sz0 = bz, sr0 = br, sh0 = b1h;                                    \
      float sz1 = 0.f, sr1 = 0.f, sh1 = 0.f;                                  \
      _Pragma("unroll")                                                       \
      for (int p = 0; p < 25; ++p) {                                          \
        f16x2 hv = __builtin_bit_cast(                                        \
            f16x2, __builtin_amdgcn_ds_bpermute(p << 3, pki));                \
        if (p & 1) {                                                          \
          sz1 = dot2f(hv, uz2[p], sz1);                                       \
          sr1 = dot2f(hv, ur2[p], sr1);                                       \
          sh1 = dot2f(hv, uh2[p], sh1);                                       \
        } else {                                                              \
          sz0 = dot2f(hv, uz2[p], sz0);                                       \
          sr0 = dot2f(hv, ur2[p], sr0);                                       \
          sh0 = dot2f(hv, uh2[p], sh0);                                       \
        }                                                                     \
      }                                                                       \
      float xzf = (float)pz[P];                                               \
      float xrf = (float)pr[P];                                               \
      float xhf = (float)ph[P];                                               \
      {                                                                       \
        int tn = (t0 + (P) + 8) & (T_LEN - 1);                                \
        long o = base + (long)tn * XW_STRIDE;                                 \
        pz[P] = xw[o + lc];                                                   \
        pr[P] = xw[o + H + lc];                                               \
        ph[P] = xw[o + 2 * H + lc];                                           \
      }                                                                       \
      float az = (sz0 + sz1) + xzf;                                           \
      float ar = (sr0 + sr1) + xrf;                                           \
      float zz = rcpf(1.f + __expf(-az));                                     \
      float rr = rcpf(1.f + __expf(-ar));                                     \
      float ah = fmaf(rr, sh0 + sh1, xhf + b0h);                              \
      float th = fmaf(2.f, rcpf(1.f + __expf(-2.f * ah)), -1.f);              \
      hreg = fmaf(zz, hreg - th, th);                                         \
    }
    STEP(0) STEP(1) STEP(2) STEP(3) STEP(4) STEP(5) STEP(6) STEP(7)
#undef STEP
  }

  // LeakyReLU(0.3) + dense(50->8) + softmax, single wave, in-order LDS
  if (act) {
    fin[l] = hreg >= 0.f ? hreg : 0.3f * hreg;
  }
  if (l < 8) {
    float acc = b2[l];
#pragma unroll
    for (int j = 0; j < H; ++j) acc = fmaf(fin[j], W2[j * 8 + l], acc);
    red[l] = acc;
  }
  if (l < 8) {
    float m = red[0];
#pragma unroll
    for (int i = 1; i < 8; ++i) m = fmaxf(m, red[i]);
    float s = 0.f;
#pragma unroll
    for (int i = 0; i < 8; ++i) s += __expf(red[i] - m);
    out[b * 8 + l] = __expf(red[l] - m) / s;
  }
}

extern "C" void kernel_launch(void* const* d_in, const int* in_sizes, int n_in,
                              void* d_out, int out_size, void* d_ws, size_t ws_size,
                              hipStream_t stream) {
  const float* x = (const float*)d_in[0];
  const float* W = (const float*)d_in[1];
  const float* U = (const float*)d_in[2];
  const float* bias = (const float*)d_in[3];
  const float* W2 = (const float*)d_in[4];
  const float* b2 = (const float*)d_in[5];
  float* out = (float*)d_out;
  f16* xw = (f16*)d_ws;  // [B*T][160] f16, ~168 MB

  xw_gemm<<<4096, 256, 0, stream>>>(x, W, xw);
  gru_head64<<<256, 64, 0, stream>>>(xw, U, bias, W2, b2, out);
}

// Round 6
// 1021.678 us; speedup vs baseline: 1.0021x; 1.0021x over previous
//
#include <hip/hip_runtime.h>

typedef __attribute__((ext_vector_type(4))) float f32x4;
typedef _Float16 f16;
typedef __attribute__((ext_vector_type(2))) _Float16 f16x2;
typedef __attribute__((ext_vector_type(8))) _Float16 f16x8;

#define T_LEN 2048
#define B_SZ 256
#define FEATN 128
#define H 50
#define H3 150
#define XW_STRIDE 160

__device__ __forceinline__ float rcpf(float x) { return __builtin_amdgcn_rcpf(x); }

__device__ __forceinline__ float dot2f(f16x2 a, f16x2 b, float c) {
#if __has_builtin(__builtin_amdgcn_fdot2)
  return __builtin_amdgcn_fdot2(a, b, c, false);
#else
  return fmaf((float)a[1], (float)b[1], fmaf((float)a[0], (float)b[0], c));
#endif
}

// ---------------- Phase 1: xw[m][k] = x[m][:] @ W[:][k]  (f16 out, no bias) ----
__global__ __launch_bounds__(256) void xw_gemm(const float* __restrict__ x,
                                               const float* __restrict__ W,
                                               f16* __restrict__ xw) {
  __shared__ f16 Wt[160 * 136];  // [n][k], row stride 136 halves
  const int tid = threadIdx.x;
  for (int idx = tid; idx < FEATN * H3; idx += 256) {
    int f = idx / H3;
    int n = idx - f * H3;
    Wt[n * 136 + f] = (f16)W[idx];
  }
  for (int idx = tid; idx < 10 * FEATN; idx += 256) {  // zero-pad n = 150..159
    int n = H3 + (idx >> 7);
    int f = idx & 127;
    Wt[n * 136 + f] = (f16)0.f;
  }
  __syncthreads();

  const int wid = tid >> 6;
  const int lane = tid & 63;
  const int l15 = lane & 15;
  const int g = lane >> 4;
  const long row0 = (long)blockIdx.x * 128 + wid * 32;

  f16x8 a[2][4];
#pragma unroll
  for (int sub = 0; sub < 2; ++sub) {
    const float* xp = x + (row0 + sub * 16 + l15) * FEATN + g * 8;
#pragma unroll
    for (int kk = 0; kk < 4; ++kk) {
      f32x4 p0 = *(const f32x4*)(xp + kk * 32);
      f32x4 p1 = *(const f32x4*)(xp + kk * 32 + 4);
      f16x8 v;
      v[0] = (f16)p0[0]; v[1] = (f16)p0[1]; v[2] = (f16)p0[2]; v[3] = (f16)p0[3];
      v[4] = (f16)p1[0]; v[5] = (f16)p1[1]; v[6] = (f16)p1[2]; v[7] = (f16)p1[3];
      a[sub][kk] = v;
    }
  }

  for (int nt = 0; nt < 10; ++nt) {
    const f16* bp = &Wt[(nt * 16 + l15) * 136 + g * 8];
    f16x8 bf0 = *(const f16x8*)(bp);
    f16x8 bf1 = *(const f16x8*)(bp + 32);
    f16x8 bf2 = *(const f16x8*)(bp + 64);
    f16x8 bf3 = *(const f16x8*)(bp + 96);
    f32x4 acc0 = {0.f, 0.f, 0.f, 0.f};
    f32x4 acc1 = {0.f, 0.f, 0.f, 0.f};
    acc0 = __builtin_amdgcn_mfma_f32_16x16x32_f16(a[0][0], bf0, acc0, 0, 0, 0);
    acc0 = __builtin_amdgcn_mfma_f32_16x16x32_f16(a[0][1], bf1, acc0, 0, 0, 0);
    acc0 = __builtin_amdgcn_mfma_f32_16x16x32_f16(a[0][2], bf2, acc0, 0, 0, 0);
    acc0 = __builtin_amdgcn_mfma_f32_16x16x32_f16(a[0][3], bf3, acc0, 0, 0, 0);
    acc1 = __builtin_amdgcn_mfma_f32_16x16x32_f16(a[1][0], bf0, acc1, 0, 0, 0);
    acc1 = __builtin_amdgcn_mfma_f32_16x16x32_f16(a[1][1], bf1, acc1, 0, 0, 0);
    acc1 = __builtin_amdgcn_mfma_f32_16x16x32_f16(a[1][2], bf2, acc1, 0, 0, 0);
    acc1 = __builtin_amdgcn_mfma_f32_16x16x32_f16(a[1][3], bf3, acc1, 0, 0, 0);
    int col = nt * 16 + l15;
    if (col < H3) {
#pragma unroll
      for (int r = 0; r < 4; ++r) {
        long rowA = row0 + g * 4 + r;
        xw[rowA * XW_STRIDE + col] = (f16)acc0[r];
        xw[(rowA + 16) * XW_STRIDE + col] = (f16)acc1[r];
      }
    }
  }
}

// ---------------- Phase 2: one wave64 per row; readlane->SGPR broadcast ------
// Lane l<50 owns h[l]. Per step: DPP quad_perm fetches h[l^1], cvt_pkrtz packs
// the pair {h[2p],h[2p+1]} (valid at even lanes), then 25 v_readlane pull the
// packed pairs into SGPRs; v_dot2_f32_f16 consumes the SGPR directly (operand
// broadcast is free) — no LDS pipe on the critical path at all.
__global__ __launch_bounds__(64, 1) void gru_head64(const f16* __restrict__ xw,
                                                    const float* __restrict__ U,
                                                    const float* __restrict__ bias,
                                                    const float* __restrict__ W2,
                                                    const float* __restrict__ b2,
                                                    float* __restrict__ out) {
  __shared__ float fin[52];
  __shared__ float red[8];
  const int l = threadIdx.x;
  const int b = blockIdx.x;
  const int lc = l < H ? l : H - 1;
  const bool act = l < H;
  const long base = (long)b * T_LEN * XW_STRIDE;

  // U columns (z,r,h) for this lane, packed as f16 pairs over j: 75 VGPRs.
  f16x2 uz2[25], ur2[25], uh2[25];
#pragma unroll
  for (int c = 0; c < 25; ++c) {
    uz2[c][0] = (f16)U[(2 * c) * H3 + lc];
    uz2[c][1] = (f16)U[(2 * c + 1) * H3 + lc];
    ur2[c][0] = (f16)U[(2 * c) * H3 + H + lc];
    ur2[c][1] = (f16)U[(2 * c + 1) * H3 + H + lc];
    uh2[c][0] = (f16)U[(2 * c) * H3 + 2 * H + lc];
    uh2[c][1] = (f16)U[(2 * c + 1) * H3 + 2 * H + lc];
  }
  const float bz = bias[lc] + bias[H3 + lc];
  const float br = bias[H + lc] + bias[H3 + H + lc];
  const float b0h = bias[2 * H + lc];
  const float b1h = bias[H3 + 2 * H + lc];

  float hreg = 0.f;

  // prefetch ring, depth 8 (branch-free wrapped addresses)
  f16 pz[8], pr[8], ph[8];
#pragma unroll
  for (int p = 0; p < 8; ++p) {
    long o = base + (long)p * XW_STRIDE;
    pz[p] = xw[o + lc];
    pr[p] = xw[o + H + lc];
    ph[p] = xw[o + 2 * H + lc];
  }

  for (int t0 = 0; t0 < T_LEN; t0 += 8) {
#define STEP(P)                                                               \
    {                                                                         \
      int own = __builtin_bit_cast(int, hreg);                                \
      int par = __builtin_amdgcn_update_dpp(0, own, 0xB1, 0xF, 0xF, true);    \
      int pki = __builtin_bit_cast(                                           \
          int,                                                                \
          __builtin_amdgcn_cvt_pkrtz(hreg, __builtin_bit_cast(float, par))); \
      float sz0 = bz, sr0 = br, sh0 = b1h;                                    \
      float sz1 = 0.f, sr1 = 0.f, sh1 = 0.f;                                  \
      _Pragma("unroll")                                                       \
      for (int p = 0; p < 25; ++p) {                                          \
        f16x2 hv = __builtin_bit_cast(                                        \
            f16x2, __builtin_amdgcn_readlane(pki, 2 * p));                    \
        if (p & 1) {                                                          \
          sz1 = dot2f(hv, uz2[p], sz1);                                       \
          sr1 = dot2f(hv, ur2[p], sr1);                                       \
          sh1 = dot2f(hv, uh2[p], sh1);                                       \
        } else {                                                              \
          sz0 = dot2f(hv, uz2[p], sz0);                                       \
          sr0 = dot2f(hv, ur2[p], sr0);                                       \
          sh0 = dot2f(hv, uh2[p], sh0);                                       \
        }                                                                     \
      }                                                                       \
      float xzf = (float)pz[P];                                               \
      float xrf = (float)pr[P];                                               \
      float xhf = (float)ph[P];                                               \
      {                                                                       \
        int tn = (t0 + (P) + 8) & (T_LEN - 1);                                \
        long o = base + (long)tn * XW_STRIDE;                                 \
        pz[P] = xw[o + lc];                                                   \
        pr[P] = xw[o + H + lc];                                               \
        ph[P] = xw[o + 2 * H + lc];                                           \
      }                                                                       \
      float az = (sz0 + sz1) + xzf;                                           \
      float ar = (sr0 + sr1) + xrf;                                           \
      float zz = rcpf(1.f + __expf(-az));                                     \
      float rr = rcpf(1.f + __expf(-ar));                                     \
      float ah = fmaf(rr, sh0 + sh1, xhf + b0h);                              \
      float th = fmaf(2.f, rcpf(1.f + __expf(-2.f * ah)), -1.f);              \
      hreg = fmaf(zz, hreg - th, th);                                         \
    }
    STEP(0) STEP(1) STEP(2) STEP(3) STEP(4) STEP(5) STEP(6) STEP(7)
#undef STEP
  }

  // LeakyReLU(0.3) + dense(50->8) + softmax, single wave, in-order LDS
  if (act) {
    fin[l] = hreg >= 0.f ? hreg : 0.3f * hreg;
  }
  if (l < 8) {
    float acc = b2[l];
#pragma unroll
    for (int j = 0; j < H; ++j) acc = fmaf(fin[j], W2[j * 8 + l], acc);
    red[l] = acc;
  }
  if (l < 8) {
    float m = red[0];
#pragma unroll
    for (int i = 1; i < 8; ++i) m = fmaxf(m, red[i]);
    float s = 0.f;
#pragma unroll
    for (int i = 0; i < 8; ++i) s += __expf(red[i] - m);
    out[b * 8 + l] = __expf(red[l] - m) / s;
  }
}

extern "C" void kernel_launch(void* const* d_in, const int* in_sizes, int n_in,
                              void* d_out, int out_size, void* d_ws, size_t ws_size,
                              hipStream_t stream) {
  const float* x = (const float*)d_in[0];
  const float* W = (const float*)d_in[1];
  const float* U = (const float*)d_in[2];
  const float* bias = (const float*)d_in[3];
  const float* W2 = (const float*)d_in[4];
  const float* b2 = (const float*)d_in[5];
  float* out = (float*)d_out;
  f16* xw = (f16*)d_ws;  // [B*T][160] f16, ~168 MB

  xw_gemm<<<4096, 256, 0, stream>>>(x, W, xw);
  gru_head64<<<256, 64, 0, stream>>>(xw, U, bias, W2, b2, out);
}

// Round 8
// 724.751 us; speedup vs baseline: 1.4126x; 1.4097x over previous
//
#include <hip/hip_runtime.h>

typedef __attribute__((ext_vector_type(4))) float f32x4;
typedef _Float16 f16;
typedef __attribute__((ext_vector_type(2))) _Float16 f16x2;
typedef __attribute__((ext_vector_type(8))) _Float16 f16x8;

#define T_LEN 2048
#define B_SZ 256
#define FEATN 128
#define H 50
#define H3 150
#define XW_STRIDE 160

__device__ __forceinline__ float rcpf(float x) { return __builtin_amdgcn_rcpf(x); }

__device__ __forceinline__ float dot2f(f16x2 a, f16x2 b, float c) {
#if __has_builtin(__builtin_amdgcn_fdot2)
  return __builtin_amdgcn_fdot2(a, b, c, false);
#else
  return fmaf((float)a[1], (float)b[1], fmaf((float)a[0], (float)b[0], c));
#endif
}

// ---------------- Phase 1: xw[m][k] = x[m][:] @ W[:][k]  (f16 out, no bias) ----
__global__ __launch_bounds__(256) void xw_gemm(const float* __restrict__ x,
                                               const float* __restrict__ W,
                                               f16* __restrict__ xw) {
  __shared__ f16 Wt[160 * 136];  // [n][k], row stride 136 halves
  const int tid = threadIdx.x;
  for (int idx = tid; idx < FEATN * H3; idx += 256) {
    int f = idx / H3;
    int n = idx - f * H3;
    Wt[n * 136 + f] = (f16)W[idx];
  }
  for (int idx = tid; idx < 10 * FEATN; idx += 256) {  // zero-pad n = 150..159
    int n = H3 + (idx >> 7);
    int f = idx & 127;
    Wt[n * 136 + f] = (f16)0.f;
  }
  __syncthreads();

  const int wid = tid >> 6;
  const int lane = tid & 63;
  const int l15 = lane & 15;
  const int g = lane >> 4;
  const long row0 = (long)blockIdx.x * 128 + wid * 32;

  f16x8 a[2][4];
#pragma unroll
  for (int sub = 0; sub < 2; ++sub) {
    const float* xp = x + (row0 + sub * 16 + l15) * FEATN + g * 8;
#pragma unroll
    for (int kk = 0; kk < 4; ++kk) {
      f32x4 p0 = *(const f32x4*)(xp + kk * 32);
      f32x4 p1 = *(const f32x4*)(xp + kk * 32 + 4);
      f16x8 v;
      v[0] = (f16)p0[0]; v[1] = (f16)p0[1]; v[2] = (f16)p0[2]; v[3] = (f16)p0[3];
      v[4] = (f16)p1[0]; v[5] = (f16)p1[1]; v[6] = (f16)p1[2]; v[7] = (f16)p1[3];
      a[sub][kk] = v;
    }
  }

  for (int nt = 0; nt < 10; ++nt) {
    const f16* bp = &Wt[(nt * 16 + l15) * 136 + g * 8];
    f16x8 bf0 = *(const f16x8*)(bp);
    f16x8 bf1 = *(const f16x8*)(bp + 32);
    f16x8 bf2 = *(const f16x8*)(bp + 64);
    f16x8 bf3 = *(const f16x8*)(bp + 96);
    f32x4 acc0 = {0.f, 0.f, 0.f, 0.f};
    f32x4 acc1 = {0.f, 0.f, 0.f, 0.f};
    acc0 = __builtin_amdgcn_mfma_f32_16x16x32_f16(a[0][0], bf0, acc0, 0, 0, 0);
    acc0 = __builtin_amdgcn_mfma_f32_16x16x32_f16(a[0][1], bf1, acc0, 0, 0, 0);
    acc0 = __builtin_amdgcn_mfma_f32_16x16x32_f16(a[0][2], bf2, acc0, 0, 0, 0);
    acc0 = __builtin_amdgcn_mfma_f32_16x16x32_f16(a[0][3], bf3, acc0, 0, 0, 0);
    acc1 = __builtin_amdgcn_mfma_f32_16x16x32_f16(a[1][0], bf0, acc1, 0, 0, 0);
    acc1 = __builtin_amdgcn_mfma_f32_16x16x32_f16(a[1][1], bf1, acc1, 0, 0, 0);
    acc1 = __builtin_amdgcn_mfma_f32_16x16x32_f16(a[1][2], bf2, acc1, 0, 0, 0);
    acc1 = __builtin_amdgcn_mfma_f32_16x16x32_f16(a[1][3], bf3, acc1, 0, 0, 0);
    int col = nt * 16 + l15;
    if (col < H3) {
#pragma unroll
      for (int r = 0; r < 4; ++r) {
        long rowA = row0 + g * 4 + r;
        xw[rowA * XW_STRIDE + col] = (f16)acc0[r];
        xw[(rowA + 16) * XW_STRIDE + col] = (f16)acc1[r];
      }
    }
  }
}

// ---------------- Phase 2: one wave64 per row; LDS h-broadcast, staggered ----
// Lane l<50 owns h[l]. h broadcast via uniform-address f16x8 (b128) LDS reads
// (same TBAA family as the f16 stores -> correct ordering; one wave's DS ops
// are in-order, no fences, vmcnt prefetch stays in flight). Gate stagger:
// r-dots -> r-sigmoid hides under h-dots -> exp(-2ah) hides under z-dots.
__global__ __launch_bounds__(64, 1) void gru_head64(const f16* __restrict__ xw,
                                                    const float* __restrict__ U,
                                                    const float* __restrict__ bias,
                                                    const float* __restrict__ W2,
                                                    const float* __restrict__ b2,
                                                    float* __restrict__ out) {
  __shared__ __align__(16) f16 h_lds16[64];
  __shared__ float fin[52];
  __shared__ float red[8];
  const int l = threadIdx.x;
  const int b = blockIdx.x;
  const int lc = l < H ? l : H - 1;
  const bool act = l < H;
  const long base = (long)b * T_LEN * XW_STRIDE;

  // U columns (z,r,h) for this lane, packed as f16 pairs over j: 75 VGPRs.
  f16x2 uz2[25], ur2[25], uh2[25];
#pragma unroll
  for (int c = 0; c < 25; ++c) {
    uz2[c][0] = (f16)U[(2 * c) * H3 + lc];
    uz2[c][1] = (f16)U[(2 * c + 1) * H3 + lc];
    ur2[c][0] = (f16)U[(2 * c) * H3 + H + lc];
    ur2[c][1] = (f16)U[(2 * c + 1) * H3 + H + lc];
    uh2[c][0] = (f16)U[(2 * c) * H3 + 2 * H + lc];
    uh2[c][1] = (f16)U[(2 * c + 1) * H3 + 2 * H + lc];
  }
  const float bz = bias[lc] + bias[H3 + lc];
  const float br = bias[H + lc] + bias[H3 + H + lc];
  const float b0h = bias[2 * H + lc];
  const float b1h = bias[H3 + 2 * H + lc];

  float hreg = 0.f;
  h_lds16[l] = (f16)0.f;

  // prefetch ring, depth 8 (branch-free wrapped addresses)
  f16 pz[8], pr[8], ph[8];
#pragma unroll
  for (int p = 0; p < 8; ++p) {
    long o = base + (long)p * XW_STRIDE;
    pz[p] = xw[o + lc];
    pr[p] = xw[o + H + lc];
    ph[p] = xw[o + 2 * H + lc];
  }

  const f16x8* hp8 = (const f16x8*)h_lds16;

  for (int t0 = 0; t0 < T_LEN; t0 += 8) {
#define STEP(P)                                                               \
    {                                                                         \
      f16x8 w0 = hp8[0], w1 = hp8[1], w2 = hp8[2];                            \
      f16x8 w3 = hp8[3], w4 = hp8[4], w5 = hp8[5];                            \
      f16x2 w6 = *(const f16x2*)(h_lds16 + 48);                               \
      float xzf = (float)pz[P];                                               \
      float xrf = (float)pr[P];                                               \
      float xhf = (float)ph[P];                                               \
      {                                                                       \
        int tn = (t0 + (P) + 8) & (T_LEN - 1);                                \
        long o = base + (long)tn * XW_STRIDE;                                 \
        pz[P] = xw[o + lc];                                                   \
        pr[P] = xw[o + H + lc];                                               \
        ph[P] = xw[o + 2 * H + lc];                                           \
      }                                                                       \
      f16x2 hv[25];                                                           \
      hv[0] = __builtin_shufflevector(w0, w0, 0, 1);                          \
      hv[1] = __builtin_shufflevector(w0, w0, 2, 3);                          \
      hv[2] = __builtin_shufflevector(w0, w0, 4, 5);                          \
      hv[3] = __builtin_shufflevector(w0, w0, 6, 7);                          \
      hv[4] = __builtin_shufflevector(w1, w1, 0, 1);                          \
      hv[5] = __builtin_shufflevector(w1, w1, 2, 3);                          \
      hv[6] = __builtin_shufflevector(w1, w1, 4, 5);                          \
      hv[7] = __builtin_shufflevector(w1, w1, 6, 7);                          \
      hv[8] = __builtin_shufflevector(w2, w2, 0, 1);                          \
      hv[9] = __builtin_shufflevector(w2, w2, 2, 3);                          \
      hv[10] = __builtin_shufflevector(w2, w2, 4, 5);                         \
      hv[11] = __builtin_shufflevector(w2, w2, 6, 7);                         \
      hv[12] = __builtin_shufflevector(w3, w3, 0, 1);                         \
      hv[13] = __builtin_shufflevector(w3, w3, 2, 3);                         \
      hv[14] = __builtin_shufflevector(w3, w3, 4, 5);                         \
      hv[15] = __builtin_shufflevector(w3, w3, 6, 7);                         \
      hv[16] = __builtin_shufflevector(w4, w4, 0, 1);                         \
      hv[17] = __builtin_shufflevector(w4, w4, 2, 3);                         \
      hv[18] = __builtin_shufflevector(w4, w4, 4, 5);                         \
      hv[19] = __builtin_shufflevector(w4, w4, 6, 7);                         \
      hv[20] = __builtin_shufflevector(w5, w5, 0, 1);                         \
      hv[21] = __builtin_shufflevector(w5, w5, 2, 3);                         \
      hv[22] = __builtin_shufflevector(w5, w5, 4, 5);                         \
      hv[23] = __builtin_shufflevector(w5, w5, 6, 7);                         \
      hv[24] = w6;                                                            \
      float sr0 = br, sr1 = 0.f;                                              \
      _Pragma("unroll")                                                       \
      for (int p = 0; p < 25; ++p) {                                          \
        if (p & 1) sr1 = dot2f(hv[p], ur2[p], sr1);                           \
        else sr0 = dot2f(hv[p], ur2[p], sr0);                                 \
      }                                                                       \
      float ar = (sr0 + sr1) + xrf;                                           \
      float rr = rcpf(1.f + __expf(-ar));                                     \
      float sh0 = b1h, sh1 = 0.f;                                             \
      _Pragma("unroll")                                                       \
      for (int p = 0; p < 25; ++p) {                                          \
        if (p & 1) sh1 = dot2f(hv[p], uh2[p], sh1);                           \
        else sh0 = dot2f(hv[p], uh2[p], sh0);                                 \
      }                                                                       \
      float ah = fmaf(rr, sh0 + sh1, xhf + b0h);                              \
      float eh = __expf(-2.f * ah);                                           \
      float sz0 = bz, sz1 = 0.f;                                              \
      _Pragma("unroll")                                                       \
      for (int p = 0; p < 25; ++p) {                                          \
        if (p & 1) sz1 = dot2f(hv[p], uz2[p], sz1);                           \
        else sz0 = dot2f(hv[p], uz2[p], sz0);                                 \
      }                                                                       \
      float az = (sz0 + sz1) + xzf;                                           \
      float zz = rcpf(1.f + __expf(-az));                                     \
      float th = fmaf(2.f, rcpf(1.f + eh), -1.f);                             \
      hreg = fmaf(zz, hreg - th, th);                                         \
      h_lds16[l] = (f16)hreg;                                                 \
    }
    STEP(0) STEP(1) STEP(2) STEP(3) STEP(4) STEP(5) STEP(6) STEP(7)
#undef STEP
  }

  // LeakyReLU(0.3) + dense(50->8) + softmax, single wave, in-order LDS
  if (act) {
    fin[l] = hreg >= 0.f ? hreg : 0.3f * hreg;
  }
  if (l < 8) {
    float acc = b2[l];
#pragma unroll
    for (int j = 0; j < H; ++j) acc = fmaf(fin[j], W2[j * 8 + l], acc);
    red[l] = acc;
  }
  if (l < 8) {
    float m = red[0];
#pragma unroll
    for (int i = 1; i < 8; ++i) m = fmaxf(m, red[i]);
    float s = 0.f;
#pragma unroll
    for (int i = 0; i < 8; ++i) s += __expf(red[i] - m);
    out[b * 8 + l] = __expf(red[l] - m) / s;
  }
}

extern "C" void kernel_launch(void* const* d_in, const int* in_sizes, int n_in,
                              void* d_out, int out_size, void* d_ws, size_t ws_size,
                              hipStream_t stream) {
  const float* x = (const float*)d_in[0];
  const float* W = (const float*)d_in[1];
  const float* U = (const float*)d_in[2];
  const float* bias = (const float*)d_in[3];
  const float* W2 = (const float*)d_in[4];
  const float* b2 = (const float*)d_in[5];
  float* out = (float*)d_out;
  f16* xw = (f16*)d_ws;  // [B*T][160] f16, ~168 MB

  xw_gemm<<<4096, 256, 0, stream>>>(x, W, xw);
  gru_head64<<<256, 64, 0, stream>>>(xw, U, bias, W2, b2, out);
}

// Round 9
// 631.542 us; speedup vs baseline: 1.6211x; 1.1476x over previous
//
#include <hip/hip_runtime.h>

typedef __attribute__((ext_vector_type(4))) float f32x4;
typedef _Float16 f16;
typedef __attribute__((ext_vector_type(2))) _Float16 f16x2;
typedef __attribute__((ext_vector_type(8))) _Float16 f16x8;

#define T_LEN 2048
#define B_SZ 256
#define FEATN 128
#define H 50
#define H3 150
#define XW_STRIDE 160

__device__ __forceinline__ float rcpf(float x) { return __builtin_amdgcn_rcpf(x); }

__device__ __forceinline__ float dot2f(f16x2 a, f16x2 b, float c) {
#if __has_builtin(__builtin_amdgcn_fdot2)
  return __builtin_amdgcn_fdot2(a, b, c, false);
#else
  return fmaf((float)a[1], (float)b[1], fmaf((float)a[0], (float)b[0], c));
#endif
}

// ---------------- Phase 1: xw[m][k] = x[m][:] @ W[:][k]  (f16 out, no bias) ----
__global__ __launch_bounds__(256) void xw_gemm(const float* __restrict__ x,
                                               const float* __restrict__ W,
                                               f16* __restrict__ xw) {
  __shared__ f16 Wt[160 * 136];  // [n][k], row stride 136 halves
  const int tid = threadIdx.x;
  for (int idx = tid; idx < FEATN * H3; idx += 256) {
    int f = idx / H3;
    int n = idx - f * H3;
    Wt[n * 136 + f] = (f16)W[idx];
  }
  for (int idx = tid; idx < 10 * FEATN; idx += 256) {  // zero-pad n = 150..159
    int n = H3 + (idx >> 7);
    int f = idx & 127;
    Wt[n * 136 + f] = (f16)0.f;
  }
  __syncthreads();

  const int wid = tid >> 6;
  const int lane = tid & 63;
  const int l15 = lane & 15;
  const int g = lane >> 4;
  const long row0 = (long)blockIdx.x * 128 + wid * 32;

  f16x8 a[2][4];
#pragma unroll
  for (int sub = 0; sub < 2; ++sub) {
    const float* xp = x + (row0 + sub * 16 + l15) * FEATN + g * 8;
#pragma unroll
    for (int kk = 0; kk < 4; ++kk) {
      f32x4 p0 = *(const f32x4*)(xp + kk * 32);
      f32x4 p1 = *(const f32x4*)(xp + kk * 32 + 4);
      f16x8 v;
      v[0] = (f16)p0[0]; v[1] = (f16)p0[1]; v[2] = (f16)p0[2]; v[3] = (f16)p0[3];
      v[4] = (f16)p1[0]; v[5] = (f16)p1[1]; v[6] = (f16)p1[2]; v[7] = (f16)p1[3];
      a[sub][kk] = v;
    }
  }

  for (int nt = 0; nt < 10; ++nt) {
    const f16* bp = &Wt[(nt * 16 + l15) * 136 + g * 8];
    f16x8 bf0 = *(const f16x8*)(bp);
    f16x8 bf1 = *(const f16x8*)(bp + 32);
    f16x8 bf2 = *(const f16x8*)(bp + 64);
    f16x8 bf3 = *(const f16x8*)(bp + 96);
    f32x4 acc0 = {0.f, 0.f, 0.f, 0.f};
    f32x4 acc1 = {0.f, 0.f, 0.f, 0.f};
    acc0 = __builtin_amdgcn_mfma_f32_16x16x32_f16(a[0][0], bf0, acc0, 0, 0, 0);
    acc0 = __builtin_amdgcn_mfma_f32_16x16x32_f16(a[0][1], bf1, acc0, 0, 0, 0);
    acc0 = __builtin_amdgcn_mfma_f32_16x16x32_f16(a[0][2], bf2, acc0, 0, 0, 0);
    acc0 = __builtin_amdgcn_mfma_f32_16x16x32_f16(a[0][3], bf3, acc0, 0, 0, 0);
    acc1 = __builtin_amdgcn_mfma_f32_16x16x32_f16(a[1][0], bf0, acc1, 0, 0, 0);
    acc1 = __builtin_amdgcn_mfma_f32_16x16x32_f16(a[1][1], bf1, acc1, 0, 0, 0);
    acc1 = __builtin_amdgcn_mfma_f32_16x16x32_f16(a[1][2], bf2, acc1, 0, 0, 0);
    acc1 = __builtin_amdgcn_mfma_f32_16x16x32_f16(a[1][3], bf3, acc1, 0, 0, 0);
    int col = nt * 16 + l15;
    if (col < H3) {
#pragma unroll
      for (int r = 0; r < 4; ++r) {
        long rowA = row0 + g * 4 + r;
        xw[rowA * XW_STRIDE + col] = (f16)acc0[r];
        xw[(rowA + 16) * XW_STRIDE + col] = (f16)acc1[r];
      }
    }
  }
}

// ---------------- Phase 2: one wave64 per row (round-3 structure) ------------
// Lane l<50 owns h[l]; h broadcast via uniform-address f16x2 LDS reads (one
// wave's DS ops are in-order -> no fences; vmcnt prefetch stays in flight).
// U registers PINNED via asm so the compiler cannot rematerialize the 75
// loop-invariant loads inside the scan (round-8 counters showed VGPR=76 ->
// U was being reloaded from global every step).
__global__ __launch_bounds__(64, 1) void gru_head64(const f16* __restrict__ xw,
                                                    const float* __restrict__ U,
                                                    const float* __restrict__ bias,
                                                    const float* __restrict__ W2,
                                                    const float* __restrict__ b2,
                                                    float* __restrict__ out) {
  __shared__ __align__(4) f16 h_lds16[64];
  __shared__ float fin[52];
  __shared__ float red[8];
  const int l = threadIdx.x;
  const int b = blockIdx.x;
  const int lc = l < H ? l : H - 1;
  const bool act = l < H;
  const long base = (long)b * T_LEN * XW_STRIDE;

  // U columns (z,r,h) for this lane, packed as f16 pairs over j: 75 VGPRs.
  f16x2 uz2[25], ur2[25], uh2[25];
#pragma unroll
  for (int c = 0; c < 25; ++c) {
    uz2[c][0] = (f16)U[(2 * c) * H3 + lc];
    uz2[c][1] = (f16)U[(2 * c + 1) * H3 + lc];
    ur2[c][0] = (f16)U[(2 * c) * H3 + H + lc];
    ur2[c][1] = (f16)U[(2 * c + 1) * H3 + H + lc];
    uh2[c][0] = (f16)U[(2 * c) * H3 + 2 * H + lc];
    uh2[c][1] = (f16)U[(2 * c + 1) * H3 + 2 * H + lc];
  }
  // Pin: defs become opaque asm -> LLVM cannot sink/remat the loads into the
  // scan loop. 512-VGPR budget at launch_bounds(64,1) holds them easily.
#pragma unroll
  for (int c = 0; c < 25; ++c) {
    asm volatile("" : "+v"(uz2[c]), "+v"(ur2[c]), "+v"(uh2[c]));
  }
  float bz = bias[lc] + bias[H3 + lc];
  float br = bias[H + lc] + bias[H3 + H + lc];
  float b0h = bias[2 * H + lc];
  float b1h = bias[H3 + 2 * H + lc];
  asm volatile("" : "+v"(bz), "+v"(br), "+v"(b0h), "+v"(b1h));

  float hreg = 0.f;
  h_lds16[l] = (f16)0.f;

  // prefetch ring, depth 4 (branch-free wrapped addresses)
  f16 pz[4], pr[4], ph[4];
#pragma unroll
  for (int p = 0; p < 4; ++p) {
    long o = base + (long)p * XW_STRIDE;
    pz[p] = xw[o + lc];
    pr[p] = xw[o + H + lc];
    ph[p] = xw[o + 2 * H + lc];
  }

  const f16x2* hp2 = (const f16x2*)h_lds16;

  for (int t0 = 0; t0 < T_LEN; t0 += 4) {
#define STEP(P)                                                               \
    {                                                                         \
      float sz0 = bz, sr0 = br, sh0 = b1h;                                    \
      float sz1 = 0.f, sr1 = 0.f, sh1 = 0.f;                                  \
      _Pragma("unroll")                                                       \
      for (int p = 0; p < 25; ++p) {                                          \
        f16x2 hv = hp2[p];                                                    \
        if (p & 1) {                                                          \
          sz1 = dot2f(hv, uz2[p], sz1);                                       \
          sr1 = dot2f(hv, ur2[p], sr1);                                       \
          sh1 = dot2f(hv, uh2[p], sh1);                                       \
        } else {                                                              \
          sz0 = dot2f(hv, uz2[p], sz0);                                       \
          sr0 = dot2f(hv, ur2[p], sr0);                                       \
          sh0 = dot2f(hv, uh2[p], sh0);                                       \
        }                                                                     \
      }                                                                       \
      float xzf = (float)pz[P];                                               \
      float xrf = (float)pr[P];                                               \
      float xhf = (float)ph[P];                                               \
      {                                                                       \
        int tn = (t0 + (P) + 4) & (T_LEN - 1);                                \
        long o = base + (long)tn * XW_STRIDE;                                 \
        pz[P] = xw[o + lc];                                                   \
        pr[P] = xw[o + H + lc];                                               \
        ph[P] = xw[o + 2 * H + lc];                                           \
      }                                                                       \
      float az = (sz0 + sz1) + xzf;                                           \
      float ar = (sr0 + sr1) + xrf;                                           \
      float zz = rcpf(1.f + __expf(-az));                                     \
      float rr = rcpf(1.f + __expf(-ar));                                     \
      float ah = fmaf(rr, sh0 + sh1, xhf + b0h);                              \
      float th = fmaf(2.f, rcpf(1.f + __expf(-2.f * ah)), -1.f);              \
      hreg = fmaf(zz, hreg - th, th);                                         \
      h_lds16[l] = (f16)hreg;                                                 \
    }
    STEP(0) STEP(1) STEP(2) STEP(3)
#undef STEP
  }

  // LeakyReLU(0.3) + dense(50->8) + softmax, single wave, in-order LDS
  if (act) {
    fin[l] = hreg >= 0.f ? hreg : 0.3f * hreg;
  }
  if (l < 8) {
    float acc = b2[l];
#pragma unroll
    for (int j = 0; j < H; ++j) acc = fmaf(fin[j], W2[j * 8 + l], acc);
    red[l] = acc;
  }
  if (l < 8) {
    float m = red[0];
#pragma unroll
    for (int i = 1; i < 8; ++i) m = fmaxf(m, red[i]);
    float s = 0.f;
#pragma unroll
    for (int i = 0; i < 8; ++i) s += __expf(red[i] - m);
    out[b * 8 + l] = __expf(red[l] - m) / s;
  }
}

extern "C" void kernel_launch(void* const* d_in, const int* in_sizes, int n_in,
                              void* d_out, int out_size, void* d_ws, size_t ws_size,
                              hipStream_t stream) {
  const float* x = (const float*)d_in[0];
  const float* W = (const float*)d_in[1];
  const float* U = (const float*)d_in[2];
  const float* bias = (const float*)d_in[3];
  const float* W2 = (const float*)d_in[4];
  const float* b2 = (const float*)d_in[5];
  float* out = (float*)d_out;
  f16* xw = (f16*)d_ws;  // [B*T][160] f16, ~168 MB

  xw_gemm<<<4096, 256, 0, stream>>>(x, W, xw);
  gru_head64<<<256, 64, 0, stream>>>(xw, U, bias, W2, b2, out);
}

// Round 10
// 613.133 us; speedup vs baseline: 1.6698x; 1.0300x over previous
//
#include <hip/hip_runtime.h>

typedef __attribute__((ext_vector_type(4))) float f32x4;
typedef _Float16 f16;
typedef __attribute__((ext_vector_type(2))) _Float16 f16x2;
typedef __attribute__((ext_vector_type(8))) _Float16 f16x8;

#define T_LEN 2048
#define B_SZ 256
#define FEATN 128
#define H 50
#define H3 150
#define XW_STRIDE 160

__device__ __forceinline__ float rcpf(float x) { return __builtin_amdgcn_rcpf(x); }

__device__ __forceinline__ float dot2f(f16x2 a, f16x2 b, float c) {
#if __has_builtin(__builtin_amdgcn_fdot2)
  return __builtin_amdgcn_fdot2(a, b, c, false);
#else
  return fmaf((float)a[1], (float)b[1], fmaf((float)a[0], (float)b[0], c));
#endif
}

// ---------------- Phase 1: xw[m][k] = x[m][:] @ W[:][k]  (f16 out, no bias) ----
__global__ __launch_bounds__(256) void xw_gemm(const float* __restrict__ x,
                                               const float* __restrict__ W,
                                               f16* __restrict__ xw) {
  __shared__ f16 Wt[160 * 136];  // [n][k], row stride 136 halves
  const int tid = threadIdx.x;
  for (int idx = tid; idx < FEATN * H3; idx += 256) {
    int f = idx / H3;
    int n = idx - f * H3;
    Wt[n * 136 + f] = (f16)W[idx];
  }
  for (int idx = tid; idx < 10 * FEATN; idx += 256) {  // zero-pad n = 150..159
    int n = H3 + (idx >> 7);
    int f = idx & 127;
    Wt[n * 136 + f] = (f16)0.f;
  }
  __syncthreads();

  const int wid = tid >> 6;
  const int lane = tid & 63;
  const int l15 = lane & 15;
  const int g = lane >> 4;
  const long row0 = (long)blockIdx.x * 128 + wid * 32;

  f16x8 a[2][4];
#pragma unroll
  for (int sub = 0; sub < 2; ++sub) {
    const float* xp = x + (row0 + sub * 16 + l15) * FEATN + g * 8;
#pragma unroll
    for (int kk = 0; kk < 4; ++kk) {
      f32x4 p0 = *(const f32x4*)(xp + kk * 32);
      f32x4 p1 = *(const f32x4*)(xp + kk * 32 + 4);
      f16x8 v;
      v[0] = (f16)p0[0]; v[1] = (f16)p0[1]; v[2] = (f16)p0[2]; v[3] = (f16)p0[3];
      v[4] = (f16)p1[0]; v[5] = (f16)p1[1]; v[6] = (f16)p1[2]; v[7] = (f16)p1[3];
      a[sub][kk] = v;
    }
  }

  for (int nt = 0; nt < 10; ++nt) {
    const f16* bp = &Wt[(nt * 16 + l15) * 136 + g * 8];
    f16x8 bf0 = *(const f16x8*)(bp);
    f16x8 bf1 = *(const f16x8*)(bp + 32);
    f16x8 bf2 = *(const f16x8*)(bp + 64);
    f16x8 bf3 = *(const f16x8*)(bp + 96);
    f32x4 acc0 = {0.f, 0.f, 0.f, 0.f};
    f32x4 acc1 = {0.f, 0.f, 0.f, 0.f};
    acc0 = __builtin_amdgcn_mfma_f32_16x16x32_f16(a[0][0], bf0, acc0, 0, 0, 0);
    acc0 = __builtin_amdgcn_mfma_f32_16x16x32_f16(a[0][1], bf1, acc0, 0, 0, 0);
    acc0 = __builtin_amdgcn_mfma_f32_16x16x32_f16(a[0][2], bf2, acc0, 0, 0, 0);
    acc0 = __builtin_amdgcn_mfma_f32_16x16x32_f16(a[0][3], bf3, acc0, 0, 0, 0);
    acc1 = __builtin_amdgcn_mfma_f32_16x16x32_f16(a[1][0], bf0, acc1, 0, 0, 0);
    acc1 = __builtin_amdgcn_mfma_f32_16x16x32_f16(a[1][1], bf1, acc1, 0, 0, 0);
    acc1 = __builtin_amdgcn_mfma_f32_16x16x32_f16(a[1][2], bf2, acc1, 0, 0, 0);
    acc1 = __builtin_amdgcn_mfma_f32_16x16x32_f16(a[1][3], bf3, acc1, 0, 0, 0);
    int col = nt * 16 + l15;
    if (col < H3) {
#pragma unroll
      for (int r = 0; r < 4; ++r) {
        long rowA = row0 + g * 4 + r;
        xw[rowA * XW_STRIDE + col] = (f16)acc0[r];
        xw[(rowA + 16) * XW_STRIDE + col] = (f16)acc1[r];
      }
    }
  }
}

// ---------------- Phase 2: one wave64 per row (round-3 structure) ------------
// Lane l<50 owns h[l]; h broadcast via uniform-address b128 f16x8 LDS reads
// (one wave's DS ops are in-order -> no fences; vmcnt prefetch in flight).
// U pinned IN-LOOP via no-op asm: loop-carried VGPR-constrained defs force
// arch-VGPR residency (round 9's pre-loop pin let the allocator park U in
// AGPRs -> v_accvgpr_read per use; VGPR_Count=80 was the tell).
__global__ __launch_bounds__(64, 1) void gru_head64(const f16* __restrict__ xw,
                                                    const float* __restrict__ U,
                                                    const float* __restrict__ bias,
                                                    const float* __restrict__ W2,
                                                    const float* __restrict__ b2,
                                                    float* __restrict__ out) {
  __shared__ __align__(16) f16 h_lds16[64];
  __shared__ float fin[52];
  __shared__ float red[8];
  const int l = threadIdx.x;
  const int b = blockIdx.x;
  const int lc = l < H ? l : H - 1;
  const bool act = l < H;
  const long base = (long)b * T_LEN * XW_STRIDE;

  // U columns (z,r,h) for this lane, packed as f16 pairs over j: 75 VGPRs.
  f16x2 uz2[25], ur2[25], uh2[25];
#pragma unroll
  for (int c = 0; c < 25; ++c) {
    uz2[c][0] = (f16)U[(2 * c) * H3 + lc];
    uz2[c][1] = (f16)U[(2 * c + 1) * H3 + lc];
    ur2[c][0] = (f16)U[(2 * c) * H3 + H + lc];
    ur2[c][1] = (f16)U[(2 * c + 1) * H3 + H + lc];
    uh2[c][0] = (f16)U[(2 * c) * H3 + 2 * H + lc];
    uh2[c][1] = (f16)U[(2 * c + 1) * H3 + 2 * H + lc];
  }
  float bz = bias[lc] + bias[H3 + lc];
  float br = bias[H + lc] + bias[H3 + H + lc];
  float b0h = bias[2 * H + lc];
  float b1h = bias[H3 + 2 * H + lc];

  float hreg = 0.f;
  h_lds16[l] = (f16)0.f;

  // per-lane base pointer; prefetch via compile-time immediate offsets
  const f16* q = xw + base + lc;

  // prefetch ring, depth 4
  f16 pz[4], pr[4], ph[4];
#pragma unroll
  for (int p = 0; p < 4; ++p) {
    pz[p] = q[p * XW_STRIDE];
    pr[p] = q[p * XW_STRIDE + H];
    ph[p] = q[p * XW_STRIDE + 2 * H];
  }

  const f16x8* hp8 = (const f16x8*)h_lds16;

#define PINS()                                                                \
  asm volatile("" : "+v"(uz2[0]), "+v"(uz2[1]), "+v"(uz2[2]), "+v"(uz2[3]),  \
                    "+v"(uz2[4]), "+v"(uz2[5]), "+v"(uz2[6]), "+v"(uz2[7]),  \
                    "+v"(uz2[8]), "+v"(uz2[9]), "+v"(uz2[10]), "+v"(uz2[11]),\
                    "+v"(uz2[12]), "+v"(uz2[13]), "+v"(uz2[14]),             \
                    "+v"(uz2[15]), "+v"(uz2[16]), "+v"(uz2[17]),             \
                    "+v"(uz2[18]), "+v"(uz2[19]), "+v"(uz2[20]),             \
                    "+v"(uz2[21]), "+v"(uz2[22]), "+v"(uz2[23]),             \
                    "+v"(uz2[24]));                                          \
  asm volatile("" : "+v"(ur2[0]), "+v"(ur2[1]), "+v"(ur2[2]), "+v"(ur2[3]),  \
                    "+v"(ur2[4]), "+v"(ur2[5]), "+v"(ur2[6]), "+v"(ur2[7]),  \
                    "+v"(ur2[8]), "+v"(ur2[9]), "+v"(ur2[10]), "+v"(ur2[11]),\
                    "+v"(ur2[12]), "+v"(ur2[13]), "+v"(ur2[14]),             \
                    "+v"(ur2[15]), "+v"(ur2[16]), "+v"(ur2[17]),             \
                    "+v"(ur2[18]), "+v"(ur2[19]), "+v"(ur2[20]),             \
                    "+v"(ur2[21]), "+v"(ur2[22]), "+v"(ur2[23]),             \
                    "+v"(ur2[24]));                                          \
  asm volatile("" : "+v"(uh2[0]), "+v"(uh2[1]), "+v"(uh2[2]), "+v"(uh2[3]),  \
                    "+v"(uh2[4]), "+v"(uh2[5]), "+v"(uh2[6]), "+v"(uh2[7]),  \
                    "+v"(uh2[8]), "+v"(uh2[9]), "+v"(uh2[10]), "+v"(uh2[11]),\
                    "+v"(uh2[12]), "+v"(uh2[13]), "+v"(uh2[14]),             \
                    "+v"(uh2[15]), "+v"(uh2[16]), "+v"(uh2[17]),             \
                    "+v"(uh2[18]), "+v"(uh2[19]), "+v"(uh2[20]),             \
                    "+v"(uh2[21]), "+v"(uh2[22]), "+v"(uh2[23]),             \
                    "+v"(uh2[24]));                                          \
  asm volatile("" : "+v"(bz), "+v"(br), "+v"(b0h), "+v"(b1h));

#define STEP(P, PF)                                                           \
    {                                                                         \
      f16x8 w0 = hp8[0], w1 = hp8[1], w2 = hp8[2];                            \
      f16x8 w3 = hp8[3], w4 = hp8[4], w5 = hp8[5];                            \
      f16x2 w6 = *(const f16x2*)(h_lds16 + 48);                               \
      f16x2 hv[25];                                                           \
      hv[0] = __builtin_shufflevector(w0, w0, 0, 1);                          \
      hv[1] = __builtin_shufflevector(w0, w0, 2, 3);                          \
      hv[2] = __builtin_shufflevector(w0, w0, 4, 5);                          \
      hv[3] = __builtin_shufflevector(w0, w0, 6, 7);                          \
      hv[4] = __builtin_shufflevector(w1, w1, 0, 1);                          \
      hv[5] = __builtin_shufflevector(w1, w1, 2, 3);                          \
      hv[6] = __builtin_shufflevector(w1, w1, 4, 5);                          \
      hv[7] = __builtin_shufflevector(w1, w1, 6, 7);                          \
      hv[8] = __builtin_shufflevector(w2, w2, 0, 1);                          \
      hv[9] = __builtin_shufflevector(w2, w2, 2, 3);                          \
      hv[10] = __builtin_shufflevector(w2, w2, 4, 5);                         \
      hv[11] = __builtin_shufflevector(w2, w2, 6, 7);                         \
      hv[12] = __builtin_shufflevector(w3, w3, 0, 1);                         \
      hv[13] = __builtin_shufflevector(w3, w3, 2, 3);                         \
      hv[14] = __builtin_shufflevector(w3, w3, 4, 5);                         \
      hv[15] = __builtin_shufflevector(w3, w3, 6, 7);                         \
      hv[16] = __builtin_shufflevector(w4, w4, 0, 1);                         \
      hv[17] = __builtin_shufflevector(w4, w4, 2, 3);                         \
      hv[18] = __builtin_shufflevector(w4, w4, 4, 5);                         \
      hv[19] = __builtin_shufflevector(w4, w4, 6, 7);                         \
      hv[20] = __builtin_shufflevector(w5, w5, 0, 1);                         \
      hv[21] = __builtin_shufflevector(w5, w5, 2, 3);                         \
      hv[22] = __builtin_shufflevector(w5, w5, 4, 5);                         \
      hv[23] = __builtin_shufflevector(w5, w5, 6, 7);                         \
      hv[24] = w6;                                                            \
      float sz0 = bz, sr0 = br, sh0 = b1h;                                    \
      float sz1 = 0.f, sr1 = 0.f, sh1 = 0.f;                                  \
      _Pragma("unroll")                                                       \
      for (int p = 0; p < 25; ++p) {                                          \
        if (p & 1) {                                                          \
          sz1 = dot2f(hv[p], uz2[p], sz1);                                    \
          sr1 = dot2f(hv[p], ur2[p], sr1);                                    \
          sh1 = dot2f(hv[p], uh2[p], sh1);                                    \
        } else {                                                              \
          sz0 = dot2f(hv[p], uz2[p], sz0);                                    \
          sr0 = dot2f(hv[p], ur2[p], sr0);                                    \
          sh0 = dot2f(hv[p], uh2[p], sh0);                                    \
        }                                                                     \
      }                                                                       \
      float xzf = (float)pz[P];                                               \
      float xrf = (float)pr[P];                                               \
      float xhf = (float)ph[P];                                               \
      if (PF) {                                                               \
        pz[P] = q[(P + 4) * XW_STRIDE];                                       \
        pr[P] = q[(P + 4) * XW_STRIDE + H];                                   \
        ph[P] = q[(P + 4) * XW_STRIDE + 2 * H];                               \
      }                                                                       \
      float ar = (sr0 + sr1) + xrf;                                           \
      float er = __expf(-ar);                                                 \
      float az = (sz0 + sz1) + xzf;                                           \
      float ez = __expf(-az);                                                 \
      float rr = rcpf(1.f + er);                                              \
      float zz = rcpf(1.f + ez);                                              \
      float ah = fmaf(rr, sh0 + sh1, xhf + b0h);                              \
      float eh = __expf(-2.f * ah);                                           \
      float th = fmaf(2.f, rcpf(1.f + eh), -1.f);                             \
      hreg = fmaf(zz, hreg - th, th);                                         \
      h_lds16[l] = (f16)hreg;                                                 \
    }

  for (int t0 = 0; t0 < T_LEN - 4; t0 += 4) {
    PINS()
    STEP(0, 1) STEP(1, 1) STEP(2, 1) STEP(3, 1)
    q += 4 * XW_STRIDE;
  }
  // final group: no prefetch (avoids OOB reads past the workspace)
  PINS()
  STEP(0, 0) STEP(1, 0) STEP(2, 0) STEP(3, 0)
#undef STEP
#undef PINS

  // LeakyReLU(0.3) + dense(50->8) + softmax, single wave, in-order LDS
  if (act) {
    fin[l] = hreg >= 0.f ? hreg : 0.3f * hreg;
  }
  if (l < 8) {
    float acc = b2[l];
#pragma unroll
    for (int j = 0; j < H; ++j) acc = fmaf(fin[j], W2[j * 8 + l], acc);
    red[l] = acc;
  }
  if (l < 8) {
    float m = red[0];
#pragma unroll
    for (int i = 1; i < 8; ++i) m = fmaxf(m, red[i]);
    float s = 0.f;
#pragma unroll
    for (int i = 0; i < 8; ++i) s += __expf(red[i] - m);
    out[b * 8 + l] = __expf(red[l] - m) / s;
  }
}

extern "C" void kernel_launch(void* const* d_in, const int* in_sizes, int n_in,
                              void* d_out, int out_size, void* d_ws, size_t ws_size,
                              hipStream_t stream) {
  const float* x = (const float*)d_in[0];
  const float* W = (const float*)d_in[1];
  const float* U = (const float*)d_in[2];
  const float* bias = (const float*)d_in[3];
  const float* W2 = (const float*)d_in[4];
  const float* b2 = (const float*)d_in[5];
  float* out = (float*)d_out;
  f16* xw = (f16*)d_ws;  // [B*T][160] f16, ~168 MB

  xw_gemm<<<4096, 256, 0, stream>>>(x, W, xw);
  gru_head64<<<256, 64, 0, stream>>>(xw, U, bias, W2, b2, out);
}